// Round 15
// baseline (128.389 us; speedup 1.0000x reference)
//
#include <hip/hip_runtime.h>
#include <hip/hip_bf16.h>

typedef unsigned short ushort_t;
typedef unsigned int uint_t;
typedef __attribute__((ext_vector_type(8))) short short8;
typedef __attribute__((ext_vector_type(4))) float f32x4;
typedef __attribute__((ext_vector_type(2))) uint_t uint2_t;

#define FOLD 128
// exp(COEFF*x^2) = 2^(-(x*S)^2);  S = sqrt(0.5/ln2)/DELTA, DELTA = 30/63
#define S_CONST 1.78357580f
#define DS_CONST 0.84932180f   /* DELTA * S_CONST = sqrt(0.5/ln2) */

__device__ __forceinline__ uint_t pkbf(float a, float b) {
    __hip_bfloat162 h2 = __float22bfloat162_rn(float2{a, b});
    uint_t u;
    __builtin_memcpy(&u, &h2, sizeof(u));
    return u;
}

// ================== bucket-sort passes (perm grouped by dst>>10) ==================
#define NB 128
#define HB 256

__global__ __launch_bounds__(256) void hist_k(const int* __restrict__ dst,
                                              int* __restrict__ hist, int E) {
    __shared__ int h[NB];
    const int t = threadIdx.x, b = blockIdx.x;
    if (t < NB) h[t] = 0;
    __syncthreads();
    const int nslice = (E + HB - 1) / HB;
    const int lo = b * nslice;
    const int hi = (lo + nslice < E) ? lo + nslice : E;
    for (int i = lo + t; i < hi; i += 256)
        atomicAdd(&h[dst[i] >> 10], 1);
    __syncthreads();
    if (t < NB) hist[b * NB + t] = h[t];
}

__global__ __launch_bounds__(128) void scan_k(const int* __restrict__ hist,
                                              int* __restrict__ off) {
    __shared__ int btot[NB], bstart[NB];
    const int t = threadIdx.x;                 // bucket id
    int s = 0;
    for (int blk = 0; blk < HB; ++blk) s += hist[blk * NB + t];
    btot[t] = s;
    __syncthreads();
    if (t == 0) {
        int run = 0;
        for (int bb = 0; bb < NB; ++bb) { bstart[bb] = run; run += btot[bb]; }
    }
    __syncthreads();
    int run = bstart[t];
    for (int blk = 0; blk < HB; ++blk) {
        off[blk * NB + t] = run;
        run += hist[blk * NB + t];
    }
}

__global__ __launch_bounds__(256) void scatter_k(const int* __restrict__ src,
                                                 const int* __restrict__ dst,
                                                 const int* __restrict__ off,
                                                 int* __restrict__ ps, int* __restrict__ pd,
                                                 int* __restrict__ pe, int E) {
    __shared__ int cnt[NB];
    const int t = threadIdx.x, b = blockIdx.x;
    if (t < NB) cnt[t] = off[b * NB + t];
    __syncthreads();
    const int nslice = (E + HB - 1) / HB;
    const int lo = b * nslice;
    const int hi = (lo + nslice < E) ? lo + nslice : E;
    for (int i = lo + t; i < hi; i += 256) {
        int d = dst[i];
        int pos = atomicAdd(&cnt[d >> 10], 1);
        ps[pos] = src[i];
        pd[pos] = d;
        pe[pos] = i;
    }
}

// ================== main fused kernel (R13 core + permuted edges) ==================
#define NWAVES 8
#define W1_OFF 0        /* 20480 dw: W1 bf16 fragment-packed */
#define W2_OFF 20480    /*  8192 dw: W2 bf16 fragment-packed */
#define B1_OFF 28672
#define B2_OFF 28800
#define H_OFF  28928    /*  8 waves x 1024 dw h-scratch */
#define LDS_DW 37120

__global__ __launch_bounds__(512) void fused(
    const float* __restrict__ lig,
    const float* __restrict__ p0, const float* __restrict__ p1,
    const float* __restrict__ p2, const float* __restrict__ p3,
    const float* __restrict__ p4,
    const float* __restrict__ W1, const float* __restrict__ W2,
    const float* __restrict__ b1, const float* __restrict__ b2,
    const int* __restrict__ ps, const int* __restrict__ pd,
    const int* __restrict__ pe,     // permuted original edge ids (nullptr -> identity)
    float* __restrict__ out, int E)
{
    extern __shared__ uint_t smem[];
    uint_t* W1L = smem + W1_OFF;
    uint_t* W2L = smem + W2_OFF;
    const float* b1L = (const float*)(smem + B1_OFF);
    const float* b2L = (const float*)(smem + B2_OFF);

    const int t = threadIdx.x;
    const int w = t >> 6;
    const int l = t & 63;
    const int eL = l & 15, g = l >> 4;
    uint_t* hw = smem + H_OFF + (w << 10);

    // ---- Stage W1/W2 bf16 fragments + biases into LDS, once ----
    for (int idx = t; idx < 20480; idx += 512) {
        int jj = idx & 3, l2 = (idx >> 2) & 63, nt = (idx >> 8) & 7, ks = idx >> 11;
        int row = ks * 32 + ((l2 >> 4) << 3) + 2 * jj;
        int col = nt * 16 + (l2 & 15);
        W1L[idx] = pkbf(W1[row * FOLD + col], W1[(row + 1) * FOLD + col]);
    }
    for (int idx = t; idx < 8192; idx += 512) {
        int jj = idx & 3, l2 = (idx >> 2) & 63, nt = (idx >> 8) & 7, ks = idx >> 11;
        int row = ks * 32 + ((l2 >> 4) << 3) + 2 * jj;
        int col = nt * 16 + (l2 & 15);
        W2L[idx] = pkbf(W2[row * FOLD + col], W2[(row + 1) * FOLD + col]);
    }
    if (t < 128) ((float*)(smem + B1_OFF))[t] = b1[t];
    else if (t < 256) ((float*)(smem + B2_OFF))[t - 128] = b2[t - 128];
    __syncthreads();   // the ONLY block barrier

    const int NT = (E + 31) >> 5;
    // XCD-swizzled contiguous chunking: XCD x owns a contiguous tile range ->
    // its L2 sees few dst-buckets (positions become L2-resident).
    const int bid = blockIdx.x;
    const int swzb = (bid & 7) * 32 + (bid >> 3);       // 256 blocks, 8 XCDs
    const int wgid = swzb * NWAVES + w;                 // 0..2047
    const int nwav = gridDim.x * NWAVES;
    const int tpw = (NT + nwav - 1) / nwav;
    int wt = wgid * tpw;
    const int wend = (wt + tpw < NT) ? wt + tpw : NT;
    if (wt >= wend) return;

    const float* GP = (g == 0) ? p0 : (g == 1) ? p1 : (g == 2) ? p2 : p3;
    const bool g0 = (g == 0);
    const float gbase = (float)(8 * g) * DS_CONST;

    // ---- Prologue: current tile indices + positions; next tile indices ----
    int peC[2];
    float Ax[2], Ay[2], Az[2], Px[2], Py[2], Pz[2], Qx[2], Qy[2], Qz[2];
    #pragma unroll
    for (int eh = 0; eh < 2; ++eh) {
        int i = wt * 32 + eh * 16 + eL; if (i >= E) i = E - 1;
        peC[eh] = pe ? pe[i] : i;
        int s = ps[i], d2 = pd[i];
        Ax[eh] = lig[3 * s]; Ay[eh] = lig[3 * s + 1]; Az[eh] = lig[3 * s + 2];
        Px[eh] = GP[3 * d2]; Py[eh] = GP[3 * d2 + 1]; Pz[eh] = GP[3 * d2 + 2];
        if (g0) { Qx[eh] = p4[3 * d2]; Qy[eh] = p4[3 * d2 + 1]; Qz[eh] = p4[3 * d2 + 2]; }
    }
    int sB[2], dB[2], peN[2];
    if (wt + 1 < wend) {
        #pragma unroll
        for (int eh = 0; eh < 2; ++eh) {
            int i = (wt + 1) * 32 + eh * 16 + eL; if (i >= E) i = E - 1;
            sB[eh] = ps[i]; dB[eh] = pd[i]; peN[eh] = pe ? pe[i] : i;
        }
    }

    while (true) {
        const bool more = (wt + 1 < wend);

        // ---- Issue indices for tile wt+2 (coalesced streaming reads) ----
        int sB2[2], dB2[2], peN2[2];
        if (wt + 2 < wend) {
            #pragma unroll
            for (int eh = 0; eh < 2; ++eh) {
                int i = (wt + 2) * 32 + eh * 16 + eL; if (i >= E) i = E - 1;
                sB2[eh] = ps[i]; dB2[eh] = pd[i]; peN2[eh] = pe ? pe[i] : i;
            }
        }

        // ---- Distances + cross-lane redistribution ----
        float u00[5][2];
        #pragma unroll
        for (int eh = 0; eh < 2; ++eh) {
            float dx = Ax[eh] - Px[eh], dy = Ay[eh] - Py[eh], dz = Az[eh] - Pz[eh];
            float dm = sqrtf(dx * dx + dy * dy + dz * dz);
            float d4 = 0.f;
            if (g0) {
                float ex = Ax[eh] - Qx[eh], ey = Ay[eh] - Qy[eh], ez = Az[eh] - Qz[eh];
                d4 = sqrtf(ex * ex + ey * ey + ez * ez);
            }
            #pragma unroll
            for (int c = 0; c < 4; ++c)
                u00[c][eh] = __builtin_fmaf(__shfl(dm, c * 16 + eL), S_CONST, -gbase);
            u00[4][eh] = __builtin_fmaf(__shfl(d4, eL), S_CONST, -gbase);
        }

        // ---- RBF expansion into register B-fragments ----
        short8 a[2][10];
        #pragma unroll
        for (int ks = 0; ks < 10; ++ks) {
            const int c = ks >> 1;
            #pragma unroll
            for (int eh = 0; eh < 2; ++eh) {
                uint_t dwv[4];
                #pragma unroll
                for (int jj = 0; jj < 4; ++jj) {
                    float k0 = (float)((ks & 1) * 32 + 2 * jj) * DS_CONST;
                    float k1 = (float)((ks & 1) * 32 + 2 * jj + 1) * DS_CONST;
                    float ua = u00[c][eh] - k0;
                    float ub = u00[c][eh] - k1;
                    float va = __builtin_amdgcn_exp2f(-(ua * ua));
                    float vb = __builtin_amdgcn_exp2f(-(ub * ub));
                    dwv[jj] = pkbf(va, vb);
                }
                __builtin_memcpy(&a[eh][ks], dwv, 16);
            }
        }

        // ---- Issue next tile's position loads (indices arrived during exp;
        //      dst now bucket-local -> L2 hits) ----
        float Bx[2], By[2], Bz[2], Rx[2], Ry[2], Rz[2], Sx[2], Sy[2], Sz[2];
        if (more) {
            #pragma unroll
            for (int eh = 0; eh < 2; ++eh) {
                Bx[eh] = lig[3 * sB[eh]]; By[eh] = lig[3 * sB[eh] + 1]; Bz[eh] = lig[3 * sB[eh] + 2];
                Rx[eh] = GP[3 * dB[eh]]; Ry[eh] = GP[3 * dB[eh] + 1]; Rz[eh] = GP[3 * dB[eh] + 2];
                if (g0) { Sx[eh] = p4[3 * dB[eh]]; Sy[eh] = p4[3 * dB[eh] + 1]; Sz[eh] = p4[3 * dB[eh] + 2]; }
            }
        }

        // ---- GEMM1 ----
        f32x4 acc1[8][2];
        #pragma unroll
        for (int nt = 0; nt < 8; ++nt)
            #pragma unroll
            for (int eh = 0; eh < 2; ++eh) acc1[nt][eh] = f32x4{0.f, 0.f, 0.f, 0.f};
        #pragma unroll
        for (int ks = 0; ks < 10; ++ks) {
            #pragma unroll
            for (int nt = 0; nt < 8; ++nt) {
                const short8 wf = *reinterpret_cast<const short8*>(&W1L[((ks * 8 + nt) * 64 + l) * 4]);
                acc1[nt][0] = __builtin_amdgcn_mfma_f32_16x16x32_bf16(wf, a[0][ks], acc1[nt][0], 0, 0, 0);
                acc1[nt][1] = __builtin_amdgcn_mfma_f32_16x16x32_bf16(wf, a[1][ks], acc1[nt][1], 0, 0, 0);
            }
        }

        // ---- Per edge-half: h round-trip, GEMM2, store (R13 form) ----
        const int swzE = (eL & 7) << 3;
        #pragma unroll
        for (int eh = 0; eh < 2; ++eh) {
            #pragma unroll
            for (int nt = 0; nt < 8; ++nt) {
                f32x4 bv = *reinterpret_cast<const f32x4*>(&b1L[nt * 16 + g * 4]);
                float v0 = fmaxf(acc1[nt][eh][0] + bv[0], 0.f);
                float v1 = fmaxf(acc1[nt][eh][1] + bv[1], 0.f);
                float v2 = fmaxf(acc1[nt][eh][2] + bv[2], 0.f);
                float v3 = fmaxf(acc1[nt][eh][3] + bv[3], 0.f);
                uint2_t pv;
                pv[0] = pkbf(v0, v1);
                pv[1] = pkbf(v2, v3);
                *reinterpret_cast<uint2_t*>(&hw[eL * 64 + ((nt * 8 + g * 2) ^ swzE)]) = pv;
            }
            f32x4 acc2[8];
            #pragma unroll
            for (int nt = 0; nt < 8; ++nt) acc2[nt] = f32x4{0.f, 0.f, 0.f, 0.f};
            #pragma unroll
            for (int ks2 = 0; ks2 < 4; ++ks2) {
                const short8 hf = *reinterpret_cast<const short8*>(&hw[eL * 64 + ((ks2 * 16 + g * 4) ^ swzE)]);
                #pragma unroll
                for (int nt = 0; nt < 8; ++nt) {
                    const short8 wf2 = *reinterpret_cast<const short8*>(&W2L[((ks2 * 8 + nt) * 64 + l) * 4]);
                    acc2[nt] = __builtin_amdgcn_mfma_f32_16x16x32_bf16(wf2, hf, acc2[nt], 0, 0, 0);
                }
            }
            const size_t eo = (size_t)peC[eh] * FOLD;
            #pragma unroll
            for (int nt = 0; nt < 8; ++nt) {
                f32x4 bv2 = *reinterpret_cast<const f32x4*>(&b2L[nt * 16 + g * 4]);
                f32x4 v = acc2[nt] + bv2;
                __builtin_nontemporal_store(v,
                    reinterpret_cast<f32x4*>(&out[eo + nt * 16 + g * 4]));
            }
            asm volatile("s_waitcnt lgkmcnt(0)" ::: "memory");
        }

        if (!more) break;
        ++wt;
        #pragma unroll
        for (int eh = 0; eh < 2; ++eh) {
            Ax[eh] = Bx[eh]; Ay[eh] = By[eh]; Az[eh] = Bz[eh];
            Px[eh] = Rx[eh]; Py[eh] = Ry[eh]; Pz[eh] = Rz[eh];
            if (g0) { Qx[eh] = Sx[eh]; Qy[eh] = Sy[eh]; Qz[eh] = Sz[eh]; }
            peC[eh] = peN[eh]; sB[eh] = sB2[eh]; dB[eh] = dB2[eh]; peN[eh] = peN2[eh];
        }
    }
}

extern "C" void kernel_launch(void* const* d_in, const int* in_sizes, int n_in,
                              void* d_out, int out_size, void* d_ws, size_t ws_size,
                              hipStream_t stream) {
    const float* lig = (const float*)d_in[0];
    const float* p0  = (const float*)d_in[1];
    const float* p1  = (const float*)d_in[2];
    const float* p2  = (const float*)d_in[3];
    const float* p3  = (const float*)d_in[4];
    const float* p4  = (const float*)d_in[5];
    const float* W1  = (const float*)d_in[6];
    const float* b1  = (const float*)d_in[7];
    const float* W2  = (const float*)d_in[8];
    const float* b2  = (const float*)d_in[9];
    const int* src   = (const int*)d_in[10];
    const int* dst   = (const int*)d_in[11];
    float* out = (float*)d_out;
    const int E = in_sizes[10];
    const int NP = in_sizes[1] / 3;

    const size_t need = (size_t)E * 3 * sizeof(int) + 2 * (size_t)(HB * NB) * sizeof(int);
    const bool useperm = (ws_size >= need) && (NP <= (NB << 10));

    const int* ps = src;
    const int* pd = dst;
    const int* pei = nullptr;
    if (useperm) {
        int* wsb = (int*)d_ws;
        int* ps_w  = wsb;
        int* pd_w  = wsb + E;
        int* pe_w  = wsb + 2 * (size_t)E;
        int* hist  = wsb + 3 * (size_t)E;
        int* off   = hist + HB * NB;
        hist_k<<<HB, 256, 0, stream>>>(dst, hist, E);
        scan_k<<<1, 128, 0, stream>>>(hist, off);
        scatter_k<<<HB, 256, 0, stream>>>(src, dst, off, ps_w, pd_w, pe_w, E);
        ps = ps_w; pd = pd_w; pei = pe_w;
    }

    hipFuncSetAttribute(reinterpret_cast<const void*>(fused),
                        hipFuncAttributeMaxDynamicSharedMemorySize, LDS_DW * 4);

    fused<<<256, 512, LDS_DW * 4, stream>>>(lig, p0, p1, p2, p3, p4, W1, W2,
                                            b1, b2, ps, pd, pei, out, E);
}

// Round 16
// 115.111 us; speedup vs baseline: 1.1153x; 1.1153x over previous
//
#include <hip/hip_runtime.h>
#include <hip/hip_bf16.h>

typedef unsigned short ushort_t;
typedef unsigned int uint_t;
typedef __attribute__((ext_vector_type(8))) short short8;
typedef __attribute__((ext_vector_type(4))) float f32x4;
typedef __attribute__((ext_vector_type(2))) uint_t uint2_t;

#define FOLD 128
// exp(COEFF*x^2) = 2^(-(x*S)^2);  S = sqrt(0.5/ln2)/DELTA, DELTA = 30/63
#define S_CONST 1.78357580f
#define DS_CONST 0.84932180f   /* DELTA * S_CONST = sqrt(0.5/ln2) */

__device__ __forceinline__ uint_t pkbf(float a, float b) {
    __hip_bfloat162 h2 = __float22bfloat162_rn(float2{a, b});
    uint_t u;
    __builtin_memcpy(&u, &h2, sizeof(u));
    return u;
}

// ---- AoS position packing: one 64B line per protein atom (all 5 channels),
//      one 16B record per ligand atom. Pure traffic reduction.
__global__ __launch_bounds__(256) void pack_pos(
    const float* __restrict__ p0, const float* __restrict__ p1,
    const float* __restrict__ p2, const float* __restrict__ p3,
    const float* __restrict__ p4, const float* __restrict__ lig,
    float* __restrict__ P5, float* __restrict__ L4, int NP, int NL)
{
    int i = blockIdx.x * 256 + threadIdx.x;
    if (i < NP) {
        float r[16];
        const float* ps0 = p0 + 3 * i; const float* ps1 = p1 + 3 * i;
        const float* ps2 = p2 + 3 * i; const float* ps3 = p3 + 3 * i;
        const float* ps4 = p4 + 3 * i;
        r[0]=ps0[0]; r[1]=ps0[1]; r[2]=ps0[2];
        r[3]=ps1[0]; r[4]=ps1[1]; r[5]=ps1[2];
        r[6]=ps2[0]; r[7]=ps2[1]; r[8]=ps2[2];
        r[9]=ps3[0]; r[10]=ps3[1]; r[11]=ps3[2];
        r[12]=ps4[0]; r[13]=ps4[1]; r[14]=ps4[2];
        r[15]=0.f;
        #pragma unroll
        for (int k = 0; k < 4; ++k)
            *reinterpret_cast<f32x4*>(&P5[(size_t)i * 16 + k * 4]) =
                *reinterpret_cast<f32x4*>(&r[k * 4]);
    } else if (i < NP + NL) {
        int j = i - NP;
        f32x4 v = {lig[3 * j], lig[3 * j + 1], lig[3 * j + 2], 0.f};
        *reinterpret_cast<f32x4*>(&L4[(size_t)j * 4]) = v;
    }
}

#define NWAVES 8
#define W1_OFF 0        /* 20480 dw: W1 bf16 fragment-packed */
#define W2_OFF 20480    /*  8192 dw: W2 bf16 fragment-packed */
#define B1_OFF 28672
#define B2_OFF 28800
#define H_OFF  28928    /*  8 waves x 1024 dw h-scratch */
#define LDS_DW 37120

// Barrier-free wave-autonomous kernel (R13 structure); PACKED selects the
// AoS gather path (P5/L4 in d_ws) vs the original 6-array path.
template<bool PACKED>
__global__ __launch_bounds__(512) void fused(
    const float* __restrict__ lig,
    const float* __restrict__ p0, const float* __restrict__ p1,
    const float* __restrict__ p2, const float* __restrict__ p3,
    const float* __restrict__ p4,
    const float* __restrict__ P5, const float* __restrict__ L4,
    const float* __restrict__ W1, const float* __restrict__ W2,
    const float* __restrict__ b1, const float* __restrict__ b2,
    const int* __restrict__ src, const int* __restrict__ dst,
    float* __restrict__ out, int E)
{
    extern __shared__ uint_t smem[];
    uint_t* W1L = smem + W1_OFF;
    uint_t* W2L = smem + W2_OFF;
    const float* b1L = (const float*)(smem + B1_OFF);
    const float* b2L = (const float*)(smem + B2_OFF);

    const int t = threadIdx.x;
    const int w = t >> 6;
    const int l = t & 63;
    const int eL = l & 15, g = l >> 4;
    uint_t* hw = smem + H_OFF + (w << 10);   // 4 KB private scratch per wave

    // ---- Stage W1/W2 bf16 fragments + biases into LDS, once ----
    for (int idx = t; idx < 20480; idx += 512) {
        int jj = idx & 3, l2 = (idx >> 2) & 63, nt = (idx >> 8) & 7, ks = idx >> 11;
        int row = ks * 32 + ((l2 >> 4) << 3) + 2 * jj;
        int col = nt * 16 + (l2 & 15);
        W1L[idx] = pkbf(W1[row * FOLD + col], W1[(row + 1) * FOLD + col]);
    }
    for (int idx = t; idx < 8192; idx += 512) {
        int jj = idx & 3, l2 = (idx >> 2) & 63, nt = (idx >> 8) & 7, ks = idx >> 11;
        int row = ks * 32 + ((l2 >> 4) << 3) + 2 * jj;
        int col = nt * 16 + (l2 & 15);
        W2L[idx] = pkbf(W2[row * FOLD + col], W2[(row + 1) * FOLD + col]);
    }
    if (t < 128) ((float*)(smem + B1_OFF))[t] = b1[t];
    else if (t < 256) ((float*)(smem + B2_OFF))[t - 128] = b2[t - 128];
    __syncthreads();   // the ONLY block barrier

    const int NT = (E + 31) >> 5;
    const int stride = gridDim.x * NWAVES;
    int wt = blockIdx.x * NWAVES + w;
    if (wt >= NT) return;

    // lane gather duty: channel g (g0 lanes also channel 4)
    const float* GP = (g == 0) ? p0 : (g == 1) ? p1 : (g == 2) ? p2 : p3;
    const float* GPp = PACKED ? (P5 + g * 3) : nullptr;   // P5[d*16 + g*3 + k]
    const bool g0 = (g == 0);
    const float gbase = (float)(8 * g) * DS_CONST;

    // ---- Prologue: idx + pos loads for first tile ----
    float Ax[2], Ay[2], Az[2], Px[2], Py[2], Pz[2], Qx[2], Qy[2], Qz[2];
    #pragma unroll
    for (int eh = 0; eh < 2; ++eh) {
        int e = wt * 32 + eh * 16 + eL; if (e >= E) e = E - 1;
        int s = src[e], d2 = dst[e];
        if constexpr (PACKED) {
            f32x4 lv = *reinterpret_cast<const f32x4*>(&L4[(size_t)s * 4]);
            Ax[eh] = lv[0]; Ay[eh] = lv[1]; Az[eh] = lv[2];
            const float* rp = GPp + (size_t)d2 * 16;
            Px[eh] = rp[0]; Py[eh] = rp[1]; Pz[eh] = rp[2];
            if (g0) {
                const float* qp = P5 + (size_t)d2 * 16 + 12;
                Qx[eh] = qp[0]; Qy[eh] = qp[1]; Qz[eh] = qp[2];
            }
        } else {
            Ax[eh] = lig[3 * s]; Ay[eh] = lig[3 * s + 1]; Az[eh] = lig[3 * s + 2];
            Px[eh] = GP[3 * d2]; Py[eh] = GP[3 * d2 + 1]; Pz[eh] = GP[3 * d2 + 2];
            if (g0) { Qx[eh] = p4[3 * d2]; Qy[eh] = p4[3 * d2 + 1]; Qz[eh] = p4[3 * d2 + 2]; }
        }
    }
    int sB[2], dB[2];
    if (wt + stride < NT) {
        #pragma unroll
        for (int eh = 0; eh < 2; ++eh) {
            int e = (wt + stride) * 32 + eh * 16 + eL; if (e >= E) e = E - 1;
            sB[eh] = src[e]; dB[eh] = dst[e];
        }
    }

    while (true) {
        const int wt2 = wt + stride;
        const bool more = (wt2 < NT);

        // ---- Issue next tile's position loads (indices already resident) ----
        float Bx[2], By[2], Bz[2], Rx[2], Ry[2], Rz[2], Sx[2], Sy[2], Sz[2];
        if (more) {
            #pragma unroll
            for (int eh = 0; eh < 2; ++eh) {
                if constexpr (PACKED) {
                    f32x4 lv = *reinterpret_cast<const f32x4*>(&L4[(size_t)sB[eh] * 4]);
                    Bx[eh] = lv[0]; By[eh] = lv[1]; Bz[eh] = lv[2];
                    const float* rp = GPp + (size_t)dB[eh] * 16;
                    Rx[eh] = rp[0]; Ry[eh] = rp[1]; Rz[eh] = rp[2];
                    if (g0) {
                        const float* qp = P5 + (size_t)dB[eh] * 16 + 12;
                        Sx[eh] = qp[0]; Sy[eh] = qp[1]; Sz[eh] = qp[2];
                    }
                } else {
                    Bx[eh] = lig[3 * sB[eh]]; By[eh] = lig[3 * sB[eh] + 1]; Bz[eh] = lig[3 * sB[eh] + 2];
                    Rx[eh] = GP[3 * dB[eh]]; Ry[eh] = GP[3 * dB[eh] + 1]; Rz[eh] = GP[3 * dB[eh] + 2];
                    if (g0) { Sx[eh] = p4[3 * dB[eh]]; Sy[eh] = p4[3 * dB[eh] + 1]; Sz[eh] = p4[3 * dB[eh] + 2]; }
                }
            }
        }
        // ---- Issue src/dst for tile wt+2*stride ----
        int sB2[2], dB2[2];
        if (wt2 + stride < NT) {
            #pragma unroll
            for (int eh = 0; eh < 2; ++eh) {
                int e = (wt2 + stride) * 32 + eh * 16 + eL; if (e >= E) e = E - 1;
                sB2[eh] = src[e]; dB2[eh] = dst[e];
            }
        }

        // ---- Distances + cross-lane redistribution ----
        float u00[5][2];
        #pragma unroll
        for (int eh = 0; eh < 2; ++eh) {
            float dx = Ax[eh] - Px[eh], dy = Ay[eh] - Py[eh], dz = Az[eh] - Pz[eh];
            float dm = sqrtf(dx * dx + dy * dy + dz * dz);
            float d4 = 0.f;
            if (g0) {
                float ex = Ax[eh] - Qx[eh], ey = Ay[eh] - Qy[eh], ez = Az[eh] - Qz[eh];
                d4 = sqrtf(ex * ex + ey * ey + ez * ez);
            }
            #pragma unroll
            for (int c = 0; c < 4; ++c)
                u00[c][eh] = __builtin_fmaf(__shfl(dm, c * 16 + eL), S_CONST, -gbase);
            u00[4][eh] = __builtin_fmaf(__shfl(d4, eL), S_CONST, -gbase);
        }

        // ---- RBF expansion into register B-fragments ----
        short8 a[2][10];
        #pragma unroll
        for (int ks = 0; ks < 10; ++ks) {
            const int c = ks >> 1;
            #pragma unroll
            for (int eh = 0; eh < 2; ++eh) {
                uint_t dwv[4];
                #pragma unroll
                for (int jj = 0; jj < 4; ++jj) {
                    float k0 = (float)((ks & 1) * 32 + 2 * jj) * DS_CONST;
                    float k1 = (float)((ks & 1) * 32 + 2 * jj + 1) * DS_CONST;
                    float ua = u00[c][eh] - k0;
                    float ub = u00[c][eh] - k1;
                    float va = __builtin_amdgcn_exp2f(-(ua * ua));
                    float vb = __builtin_amdgcn_exp2f(-(ub * ub));
                    dwv[jj] = pkbf(va, vb);
                }
                __builtin_memcpy(&a[eh][ks], dwv, 16);
            }
        }

        // ---- GEMM1 ----
        f32x4 acc1[8][2];
        #pragma unroll
        for (int nt = 0; nt < 8; ++nt)
            #pragma unroll
            for (int eh = 0; eh < 2; ++eh) acc1[nt][eh] = f32x4{0.f, 0.f, 0.f, 0.f};
        #pragma unroll
        for (int ks = 0; ks < 10; ++ks) {
            #pragma unroll
            for (int nt = 0; nt < 8; ++nt) {
                const short8 wf = *reinterpret_cast<const short8*>(&W1L[((ks * 8 + nt) * 64 + l) * 4]);
                acc1[nt][0] = __builtin_amdgcn_mfma_f32_16x16x32_bf16(wf, a[0][ks], acc1[nt][0], 0, 0, 0);
                acc1[nt][1] = __builtin_amdgcn_mfma_f32_16x16x32_bf16(wf, a[1][ks], acc1[nt][1], 0, 0, 0);
            }
        }

        // ---- Per edge-half: h round-trip, GEMM2, store ----
        const int swzE = (eL & 7) << 3;
        #pragma unroll
        for (int eh = 0; eh < 2; ++eh) {
            #pragma unroll
            for (int nt = 0; nt < 8; ++nt) {
                f32x4 bv = *reinterpret_cast<const f32x4*>(&b1L[nt * 16 + g * 4]);
                float v0 = fmaxf(acc1[nt][eh][0] + bv[0], 0.f);
                float v1 = fmaxf(acc1[nt][eh][1] + bv[1], 0.f);
                float v2 = fmaxf(acc1[nt][eh][2] + bv[2], 0.f);
                float v3 = fmaxf(acc1[nt][eh][3] + bv[3], 0.f);
                uint2_t pv;
                pv[0] = pkbf(v0, v1);
                pv[1] = pkbf(v2, v3);
                *reinterpret_cast<uint2_t*>(&hw[eL * 64 + ((nt * 8 + g * 2) ^ swzE)]) = pv;
            }
            f32x4 acc2[8];
            #pragma unroll
            for (int nt = 0; nt < 8; ++nt) acc2[nt] = f32x4{0.f, 0.f, 0.f, 0.f};
            #pragma unroll
            for (int ks2 = 0; ks2 < 4; ++ks2) {
                const short8 hf = *reinterpret_cast<const short8*>(&hw[eL * 64 + ((ks2 * 16 + g * 4) ^ swzE)]);
                #pragma unroll
                for (int nt = 0; nt < 8; ++nt) {
                    const short8 wf2 = *reinterpret_cast<const short8*>(&W2L[((ks2 * 8 + nt) * 64 + l) * 4]);
                    acc2[nt] = __builtin_amdgcn_mfma_f32_16x16x32_bf16(wf2, hf, acc2[nt], 0, 0, 0);
                }
            }
            int e = wt * 32 + eh * 16 + eL;
            if (e < E) {
                #pragma unroll
                for (int nt = 0; nt < 8; ++nt) {
                    f32x4 bv2 = *reinterpret_cast<const f32x4*>(&b2L[nt * 16 + g * 4]);
                    f32x4 v = acc2[nt] + bv2;
                    __builtin_nontemporal_store(v,
                        reinterpret_cast<f32x4*>(&out[(size_t)e * FOLD + nt * 16 + g * 4]));
                }
            }
            asm volatile("s_waitcnt lgkmcnt(0)" ::: "memory");
        }

        if (!more) break;
        wt = wt2;
        #pragma unroll
        for (int eh = 0; eh < 2; ++eh) {
            Ax[eh] = Bx[eh]; Ay[eh] = By[eh]; Az[eh] = Bz[eh];
            Px[eh] = Rx[eh]; Py[eh] = Ry[eh]; Pz[eh] = Rz[eh];
            if (g0) { Qx[eh] = Sx[eh]; Qy[eh] = Sy[eh]; Qz[eh] = Sz[eh]; }
            sB[eh] = sB2[eh]; dB[eh] = dB2[eh];
        }
    }
}

extern "C" void kernel_launch(void* const* d_in, const int* in_sizes, int n_in,
                              void* d_out, int out_size, void* d_ws, size_t ws_size,
                              hipStream_t stream) {
    const float* lig = (const float*)d_in[0];
    const float* p0  = (const float*)d_in[1];
    const float* p1  = (const float*)d_in[2];
    const float* p2  = (const float*)d_in[3];
    const float* p3  = (const float*)d_in[4];
    const float* p4  = (const float*)d_in[5];
    const float* W1  = (const float*)d_in[6];
    const float* b1  = (const float*)d_in[7];
    const float* W2  = (const float*)d_in[8];
    const float* b2  = (const float*)d_in[9];
    const int* src   = (const int*)d_in[10];
    const int* dst   = (const int*)d_in[11];
    float* out = (float*)d_out;
    const int E  = in_sizes[10];
    const int NL = in_sizes[0] / 3;
    const int NP = in_sizes[1] / 3;

    const size_t need = ((size_t)NP * 16 + (size_t)NL * 4) * sizeof(float);
    const bool packed = (ws_size >= need);

    hipFuncSetAttribute(reinterpret_cast<const void*>(fused<true>),
                        hipFuncAttributeMaxDynamicSharedMemorySize, LDS_DW * 4);
    hipFuncSetAttribute(reinterpret_cast<const void*>(fused<false>),
                        hipFuncAttributeMaxDynamicSharedMemorySize, LDS_DW * 4);

    if (packed) {
        float* P5 = (float*)d_ws;
        float* L4 = P5 + (size_t)NP * 16;
        pack_pos<<<(NP + NL + 255) / 256, 256, 0, stream>>>(p0, p1, p2, p3, p4, lig,
                                                            P5, L4, NP, NL);
        fused<true><<<256, 512, LDS_DW * 4, stream>>>(lig, p0, p1, p2, p3, p4, P5, L4,
                                                      W1, W2, b1, b2, src, dst, out, E);
    } else {
        fused<false><<<256, 512, LDS_DW * 4, stream>>>(lig, p0, p1, p2, p3, p4,
                                                       nullptr, nullptr,
                                                       W1, W2, b1, b2, src, dst, out, E);
    }
}